// Round 6
// baseline (263.288 us; speedup 1.0000x reference)
//
#include <hip/hip_runtime.h>
#include <math.h>

// DeepseekV3 TopK router, MI355X — R6: 8 lanes/token, one 32-expert group per
// lane. Per-lane: 4x stable sort-8 networks + ordered merges (replaces the
// serial insertion sort). Single __syncthreads: lanes publish group score +
// sorted top-8 to LDS once, then each lane selects the top-4 groups and
// merges exactly those 4 lists. No masking needed (zeros never reach top-8).

constexpr int N_EXPERTS  = 256;
constexpr int N_GROUP    = 8;
constexpr int EG         = 32;   // experts per group
constexpr int TOPK_GROUP = 4;
constexpr int TOP_K      = 8;
constexpr int BLOCK      = 256;

// Stable descending sort of 8 via odd-even transposition (adjacent
// comparators, strict '>' swap). Adjacent-only + no-swap-on-tie => stable:
// equal values keep ascending-index order. 28 comparators, depth 8.
__device__ __forceinline__ void sort8_stable(float (&v)[8], float (&i)[8]) {
#pragma unroll
  for (int r = 0; r < 8; ++r) {
#pragma unroll
    for (int k = (r & 1); k + 1 < 8; k += 2) {
      const bool sw = v[k + 1] > v[k];
      const float tv = sw ? v[k + 1] : v[k];
      const float bv = sw ? v[k]     : v[k + 1];
      const float ti = sw ? i[k + 1] : i[k];
      const float bi = sw ? i[k]     : i[k + 1];
      v[k] = tv; v[k + 1] = bv; i[k] = ti; i[k + 1] = bi;
    }
  }
}

// Exact total order (value desc, index asc) — for mixed-origin comparisons.
__device__ __forceinline__ bool keyGE(float va, float ia, float vb, float ib) {
  return (va > vb) || (va == vb && ia < ib);
}

__device__ __forceinline__ void cswapKey(float& va, float& ia, float& vb, float& ib) {
  const bool a = keyGE(va, ia, vb, ib);
  const float v1 = a ? va : vb, i1 = a ? ia : ib;
  const float v2 = a ? vb : va, i2 = a ? ib : ia;
  va = v1; ia = i1; vb = v2; ib = i2;
}

// Top-8 of two descending sorted-8 lists where EVERY A index < EVERY B index.
// Stage 1 tie -> A (lower index) via a single '>=' compare. Result replaces A.
__device__ __forceinline__ void merge8AB(float (&Av)[8], float (&Ai)[8],
                                         const float (&Bv)[8], const float (&Bi)[8]) {
  float Rv[8], Ri[8];
#pragma unroll
  for (int i = 0; i < 8; ++i) {
    const bool a = (Av[i] >= Bv[7 - i]);
    Rv[i] = a ? Av[i] : Bv[7 - i];
    Ri[i] = a ? Ai[i] : Bi[7 - i];
  }
  // bitonic cleanup, distances 4,2,1 — exact (value,index) order on ties
#pragma unroll
  for (int i = 0; i < 4; ++i) cswapKey(Rv[i], Ri[i], Rv[i + 4], Ri[i + 4]);
  cswapKey(Rv[0], Ri[0], Rv[2], Ri[2]);
  cswapKey(Rv[1], Ri[1], Rv[3], Ri[3]);
  cswapKey(Rv[4], Ri[4], Rv[6], Ri[6]);
  cswapKey(Rv[5], Ri[5], Rv[7], Ri[7]);
  cswapKey(Rv[0], Ri[0], Rv[1], Ri[1]);
  cswapKey(Rv[2], Ri[2], Rv[3], Ri[3]);
  cswapKey(Rv[4], Ri[4], Rv[5], Ri[5]);
  cswapKey(Rv[6], Ri[6], Rv[7], Ri[7]);
#pragma unroll
  for (int i = 0; i < 8; ++i) { Av[i] = Rv[i]; Ai[i] = Ri[i]; }
}

__global__ __launch_bounds__(256, 4) void deepseek_topk_router_r6(
    const float* __restrict__ logits,
    const float* __restrict__ bias,
    float* __restrict__ out,   // [T*8] indices (as float) then [T*8] weights
    int T) {
  // LDS: one publish, one barrier, read-only after. 17 KB total.
  __shared__ float gsb[BLOCK];                          // group scores
  __shared__ __align__(16) float exv[BLOCK * 8];        // sorted-8 values
  __shared__ __align__(16) float exi[BLOCK * 8];        // sorted-8 indices

  const int tid = threadIdx.x;
  const int id  = blockIdx.x * BLOCK + tid;
  const int t   = id >> 3;              // token (grid exact: T*8 % 256 == 0)
  const int q   = id & 7;               // group handled by this lane

  const float4* row4 =
      reinterpret_cast<const float4*>(logits + (size_t)t * N_EXPERTS + q * EG);
  const float4* b4 = reinterpret_cast<const float4*>(bias + q * EG);
  const float basef = (float)(q * EG);

  // ---- Phase A: stable-sorted top-8 of my group's 32 corrected scores ----
  float Tv[8], Ti[8];
  {
    const float4 x0 = row4[0], x1 = row4[1];
    const float4 c0 = b4[0],   c1 = b4[1];
    const float xs[8] = {x0.x, x0.y, x0.z, x0.w, x1.x, x1.y, x1.z, x1.w};
    const float bs[8] = {c0.x, c0.y, c0.z, c0.w, c1.x, c1.y, c1.z, c1.w};
#pragma unroll
    for (int j = 0; j < 8; ++j) {
      Tv[j] = 1.0f / (1.0f + expf(-xs[j])) + bs[j];  // precise fp32 sigmoid
      Ti[j] = basef + (float)j;
    }
    sort8_stable(Tv, Ti);
  }
#pragma unroll
  for (int c = 1; c < 4; ++c) {
    float Cv[8], Ci[8];
    const float4 x0 = row4[2 * c], x1 = row4[2 * c + 1];
    const float4 c0 = b4[2 * c],   c1 = b4[2 * c + 1];
    const float xs[8] = {x0.x, x0.y, x0.z, x0.w, x1.x, x1.y, x1.z, x1.w};
    const float bs[8] = {c0.x, c0.y, c0.z, c0.w, c1.x, c1.y, c1.z, c1.w};
#pragma unroll
    for (int j = 0; j < 8; ++j) {
      Cv[j] = 1.0f / (1.0f + expf(-xs[j])) + bs[j];
      Ci[j] = basef + (float)(c * 8 + j);
    }
    sort8_stable(Cv, Ci);
    merge8AB(Tv, Ti, Cv, Ci);   // running-list indices all < chunk indices
  }

  // ---- Publish: group score + sorted list. ONE barrier for the kernel. ----
  gsb[tid] = Tv[0] + Tv[1];
#pragma unroll
  for (int k = 0; k < 8; ++k) {
    exv[tid * 8 + k] = Tv[k];
    exi[tid * 8 + k] = Ti[k];
  }
  __syncthreads();

  // ---- Group selection: every lane computes the top-4 group set ----
  const int cb = tid & ~7;              // cluster base thread
  float g[N_GROUP];
#pragma unroll
  for (int h = 0; h < N_GROUP; ++h) g[h] = gsb[cb + h];

  int s0 = 0, s1 = 0, s2 = 0, s3 = 0;   // selected groups, ascending
  int cnt = 0;
#pragma unroll
  for (int h = 0; h < N_GROUP; ++h) {
    int rank = 0;
#pragma unroll
    for (int m = 0; m < N_GROUP; ++m)
      rank += (m < h) ? (g[m] >= g[h] ? 1 : 0) : (g[m] > g[h] ? 1 : 0);
    const bool pick = (rank < TOPK_GROUP);
    s0 = (pick && cnt == 0) ? h : s0;
    s1 = (pick && cnt == 1) ? h : s1;
    s2 = (pick && cnt == 2) ? h : s2;
    s3 = (pick && cnt == 3) ? h : s3;
    cnt += pick ? 1 : 0;
  }

  // ---- Merge the 4 selected lists (ascending group order) ----
  float Mv[8], Mi[8], Bv[8], Bi[8], Nv[8], Ni[8];
  {
    const float4* pv = reinterpret_cast<const float4*>(&exv[(cb + s0) * 8]);
    const float4* pi = reinterpret_cast<const float4*>(&exi[(cb + s0) * 8]);
    const float4 a = pv[0], b = pv[1], c = pi[0], d = pi[1];
    Mv[0]=a.x; Mv[1]=a.y; Mv[2]=a.z; Mv[3]=a.w; Mv[4]=b.x; Mv[5]=b.y; Mv[6]=b.z; Mv[7]=b.w;
    Mi[0]=c.x; Mi[1]=c.y; Mi[2]=c.z; Mi[3]=c.w; Mi[4]=d.x; Mi[5]=d.y; Mi[6]=d.z; Mi[7]=d.w;
  }
  {
    const float4* pv = reinterpret_cast<const float4*>(&exv[(cb + s1) * 8]);
    const float4* pi = reinterpret_cast<const float4*>(&exi[(cb + s1) * 8]);
    const float4 a = pv[0], b = pv[1], c = pi[0], d = pi[1];
    Bv[0]=a.x; Bv[1]=a.y; Bv[2]=a.z; Bv[3]=a.w; Bv[4]=b.x; Bv[5]=b.y; Bv[6]=b.z; Bv[7]=b.w;
    Bi[0]=c.x; Bi[1]=c.y; Bi[2]=c.z; Bi[3]=c.w; Bi[4]=d.x; Bi[5]=d.y; Bi[6]=d.z; Bi[7]=d.w;
  }
  merge8AB(Mv, Mi, Bv, Bi);             // m01 (s0 idx < s1 idx)
  {
    const float4* pv = reinterpret_cast<const float4*>(&exv[(cb + s2) * 8]);
    const float4* pi = reinterpret_cast<const float4*>(&exi[(cb + s2) * 8]);
    const float4 a = pv[0], b = pv[1], c = pi[0], d = pi[1];
    Bv[0]=a.x; Bv[1]=a.y; Bv[2]=a.z; Bv[3]=a.w; Bv[4]=b.x; Bv[5]=b.y; Bv[6]=b.z; Bv[7]=b.w;
    Bi[0]=c.x; Bi[1]=c.y; Bi[2]=c.z; Bi[3]=c.w; Bi[4]=d.x; Bi[5]=d.y; Bi[6]=d.z; Bi[7]=d.w;
  }
  {
    const float4* pv = reinterpret_cast<const float4*>(&exv[(cb + s3) * 8]);
    const float4* pi = reinterpret_cast<const float4*>(&exi[(cb + s3) * 8]);
    const float4 a = pv[0], b = pv[1], c = pi[0], d = pi[1];
    Nv[0]=a.x; Nv[1]=a.y; Nv[2]=a.z; Nv[3]=a.w; Nv[4]=b.x; Nv[5]=b.y; Nv[6]=b.z; Nv[7]=b.w;
    Ni[0]=c.x; Ni[1]=c.y; Ni[2]=c.z; Ni[3]=c.w; Ni[4]=d.x; Ni[5]=d.y; Ni[6]=d.z; Ni[7]=d.w;
  }
  merge8AB(Bv, Bi, Nv, Ni);             // m23 (s2 idx < s3 idx)
  merge8AB(Mv, Mi, Bv, Bi);             // final (s0,s1 idx < s2,s3 idx)

  // ---- Epilogue: weights = (c - bias[idx]) normalized * 2.5 ----
  float sv[8];
  float sum = 0.0f;
#pragma unroll
  for (int k = 0; k < TOP_K; ++k) {
    const int idf = (int)Mi[k];
    sv[k] = Mv[k] - bias[idf];          // recover sigmoid score (L1-hot)
    sum += sv[k];
  }
  const float scale = 2.5f / (sum + 1e-20f);

  // output: indices (as float) at [0, T*8), weights at [T*8, 2*T*8)
  if (q < 4) {
    float4 vout;
    if (q == 0)      vout = make_float4(Mi[0], Mi[1], Mi[2], Mi[3]);
    else if (q == 1) vout = make_float4(Mi[4], Mi[5], Mi[6], Mi[7]);
    else if (q == 2) vout = make_float4(sv[0] * scale, sv[1] * scale,
                                        sv[2] * scale, sv[3] * scale);
    else             vout = make_float4(sv[4] * scale, sv[5] * scale,
                                        sv[6] * scale, sv[7] * scale);
    const size_t half = (q < 2) ? 0 : (size_t)T * TOP_K;
    const int    sub  = q & 1;
    float4* dst = reinterpret_cast<float4*>(out + half) + (size_t)t * 2 + sub;
    *dst = vout;
  }
}

extern "C" void kernel_launch(void* const* d_in, const int* in_sizes, int n_in,
                              void* d_out, int out_size, void* d_ws, size_t ws_size,
                              hipStream_t stream) {
  const float* logits = (const float*)d_in[0];
  const float* bias   = (const float*)d_in[1];
  float* out = (float*)d_out;
  const int T = in_sizes[0] / N_EXPERTS;           // 131072 (multiple of 32)
  const long threads = (long)T * N_GROUP;          // 8 lanes per token
  const int blocks = (int)((threads + BLOCK - 1) / BLOCK);
  deepseek_topk_router_r6<<<blocks, BLOCK, 0, stream>>>(logits, bias, out, T);
}

// Round 7
// 212.231 us; speedup vs baseline: 1.2406x; 1.2406x over previous
//
#include <hip/hip_runtime.h>
#include <math.h>

// DeepseekV3 TopK router, MI355X — R7.
// Phase A: 8 lanes/token (one 32-expert group per lane), u64 packed keys
//   (monotone float bits << 32 | (255-idx)) -> exact total order incl. ties,
//   Batcher sort-8 (19 comparators) + top-8 merges (20 comparators).
// One barrier. Phase B: wave 0 only, 1 thread per token (64 tokens/block):
//   group top-4 selection + 3 key-merges + epilogue + all stores.
// Numerics frozen to the proven path: expf + IEEE 1.0f/(1+e).

constexpr int N_EXPERTS  = 256;
constexpr int N_GROUP    = 8;
constexpr int EG         = 32;
constexpr int TOPK_GROUP = 4;
constexpr int TOP_K      = 8;
constexpr int BLOCK      = 512;              // 64 tokens per block
constexpr int TPB_TOK    = BLOCK / N_GROUP;  // 64

typedef unsigned int u32;
typedef unsigned long long u64;

// monotone map: a<b (float) <=> M(a)<M(b) (u32)
__device__ __forceinline__ u32 fmono(float f) {
  const u32 u = __float_as_uint(f);
  return u ^ ((u32)((int)u >> 31) | 0x80000000u);
}
__device__ __forceinline__ float fmono_inv(u32 m) {
  const u32 u = (m & 0x80000000u) ? (m ^ 0x80000000u) : ~m;
  return __uint_as_float(u);
}
// key: larger = (bigger value, then smaller index)
__device__ __forceinline__ u64 mkkey(float v, int idx) {
  return ((u64)fmono(v) << 32) | (u32)(255 - idx);
}
__device__ __forceinline__ int key_idx(u64 k) { return 255 - (int)(k & 0xFFu); }
__device__ __forceinline__ float key_val(u64 k) { return fmono_inv((u32)(k >> 32)); }

// descending compare-swap: larger key to a
__device__ __forceinline__ void kswap(u64& a, u64& b) {
  const bool sw = b > a;
  const u64 t = sw ? b : a;
  b = sw ? a : b;
  a = t;
}

// Batcher odd-even mergesort network for 8 (19 comparators), descending.
__device__ __forceinline__ void sort8(u64 (&k)[8]) {
  kswap(k[0], k[1]); kswap(k[2], k[3]); kswap(k[4], k[5]); kswap(k[6], k[7]);
  kswap(k[0], k[2]); kswap(k[1], k[3]); kswap(k[4], k[6]); kswap(k[5], k[7]);
  kswap(k[1], k[2]); kswap(k[5], k[6]);
  kswap(k[0], k[4]); kswap(k[1], k[5]); kswap(k[2], k[6]); kswap(k[3], k[7]);
  kswap(k[2], k[4]); kswap(k[3], k[5]);
  kswap(k[1], k[2]); kswap(k[3], k[4]); kswap(k[5], k[6]);
}

// A = top-8 of (A, B); both descending sorted. Keys are unique -> exact.
__device__ __forceinline__ void merge8(u64 (&A)[8], const u64 (&B)[8]) {
  u64 R[8];
#pragma unroll
  for (int i = 0; i < 8; ++i) {
    const bool a = A[i] >= B[7 - i];
    R[i] = a ? A[i] : B[7 - i];
  }
  kswap(R[0], R[4]); kswap(R[1], R[5]); kswap(R[2], R[6]); kswap(R[3], R[7]);
  kswap(R[0], R[2]); kswap(R[1], R[3]); kswap(R[4], R[6]); kswap(R[5], R[7]);
  kswap(R[0], R[1]); kswap(R[2], R[3]); kswap(R[4], R[5]); kswap(R[6], R[7]);
#pragma unroll
  for (int i = 0; i < 8; ++i) A[i] = R[i];
}

__global__ __launch_bounds__(BLOCK, 2) void deepseek_topk_router_r7(
    const float* __restrict__ logits,
    const float* __restrict__ bias,
    float* __restrict__ out,   // [T*8] indices (as float) then [T*8] weights
    int T) {
  __shared__ __align__(16) float gsb[BLOCK];          // 2 KB group scores
  __shared__ u64 kbuf[N_GROUP][BLOCK];                // 32 KB sorted lists

  const int tid = threadIdx.x;
  const int id  = blockIdx.x * BLOCK + tid;
  const int t   = id >> 3;              // token (T*8 % 512 == 0, grid exact)
  const int q   = id & 7;               // group handled by this lane

  const float4* row4 =
      reinterpret_cast<const float4*>(logits + (size_t)t * N_EXPERTS + q * EG);
  const float4* b4 = reinterpret_cast<const float4*>(bias + q * EG);

  // ---- Phase A: sorted top-8 keys of my group's 32 corrected scores ----
  u64 K[8];
#pragma unroll
  for (int c = 0; c < 4; ++c) {
    u64 C[8];
    const float4 x0 = row4[2 * c], x1 = row4[2 * c + 1];
    const float4 c0 = b4[2 * c],   c1 = b4[2 * c + 1];
    const float xs[8] = {x0.x, x0.y, x0.z, x0.w, x1.x, x1.y, x1.z, x1.w};
    const float bs[8] = {c0.x, c0.y, c0.z, c0.w, c1.x, c1.y, c1.z, c1.w};
#pragma unroll
    for (int j = 0; j < 8; ++j) {
      const float e = expf(-xs[j]);                 // frozen numerics
      const float s = 1.0f / (1.0f + e);            // IEEE divide
      C[j] = mkkey(s + bs[j], q * EG + c * 8 + j);
    }
    sort8(C);
    if (c == 0) {
#pragma unroll
      for (int j = 0; j < 8; ++j) K[j] = C[j];
    } else {
      merge8(K, C);
    }
  }

  // ---- Publish group score + sorted list; single barrier ----
  gsb[tid] = key_val(K[0]) + key_val(K[1]);
#pragma unroll
  for (int k = 0; k < 8; ++k) kbuf[k][tid] = K[k];
  __syncthreads();
  if (tid >= TPB_TOK) return;           // waves 1..7 done

  // ---- Phase B: wave 0, one thread per token ----
  const int j   = tid;                  // local token
  const int tok = blockIdx.x * TPB_TOK + j;

  // 8 group scores (contiguous in gsb)
  const float4* gp = reinterpret_cast<const float4*>(&gsb[8 * j]);
  const float4 ga = gp[0], gb = gp[1];
  const float g[N_GROUP] = {ga.x, ga.y, ga.z, ga.w, gb.x, gb.y, gb.z, gb.w};

  // top-4 groups (ties -> lower index), collected in ascending group order
  int s0 = 0, s1 = 0, s2 = 0, s3 = 0, cnt = 0;
#pragma unroll
  for (int h = 0; h < N_GROUP; ++h) {
    int rank = 0;
#pragma unroll
    for (int m = 0; m < N_GROUP; ++m)
      rank += (m < h) ? (g[m] >= g[h] ? 1 : 0) : (g[m] > g[h] ? 1 : 0);
    const bool pick = (rank < TOPK_GROUP);
    s0 = (pick && cnt == 0) ? h : s0;
    s1 = (pick && cnt == 1) ? h : s1;
    s2 = (pick && cnt == 2) ? h : s2;
    s3 = (pick && cnt == 3) ? h : s3;
    cnt += pick ? 1 : 0;
  }

  // merge the 4 selected lists (key order is exact; any merge order OK)
  u64 A[8], B[8];
  const int base = 8 * j;
#pragma unroll
  for (int k = 0; k < 8; ++k) A[k] = kbuf[k][base + s0];
#pragma unroll
  for (int k = 0; k < 8; ++k) B[k] = kbuf[k][base + s1];
  merge8(A, B);
#pragma unroll
  for (int k = 0; k < 8; ++k) B[k] = kbuf[k][base + s2];
  merge8(A, B);
#pragma unroll
  for (int k = 0; k < 8; ++k) B[k] = kbuf[k][base + s3];
  merge8(A, B);

  // ---- Epilogue: weights = (c - bias[idx]) / sum * 2.5 ----
  float fi[8], sv[8];
  float sum = 0.0f;
#pragma unroll
  for (int k = 0; k < TOP_K; ++k) {
    const int idx = key_idx(A[k]);
    const float c = key_val(A[k]);
    sv[k] = c - bias[idx];              // recover sigmoid score (bias L1-hot)
    fi[k] = (float)idx;
    sum += sv[k];
  }
  const float scale = 2.5f / (sum + 1e-20f);

  float4* oi = reinterpret_cast<float4*>(out) + (size_t)tok * 2;
  oi[0] = make_float4(fi[0], fi[1], fi[2], fi[3]);
  oi[1] = make_float4(fi[4], fi[5], fi[6], fi[7]);
  float4* ow = reinterpret_cast<float4*>(out + (size_t)T * TOP_K) + (size_t)tok * 2;
  ow[0] = make_float4(sv[0] * scale, sv[1] * scale, sv[2] * scale, sv[3] * scale);
  ow[1] = make_float4(sv[4] * scale, sv[5] * scale, sv[6] * scale, sv[7] * scale);
}

extern "C" void kernel_launch(void* const* d_in, const int* in_sizes, int n_in,
                              void* d_out, int out_size, void* d_ws, size_t ws_size,
                              hipStream_t stream) {
  const float* logits = (const float*)d_in[0];
  const float* bias   = (const float*)d_in[1];
  float* out = (float*)d_out;
  const int T = in_sizes[0] / N_EXPERTS;           // 131072 (multiple of 64)
  const int blocks = T / TPB_TOK;                   // 2048
  deepseek_topk_router_r7<<<blocks, BLOCK, 0, stream>>>(logits, bias, out, T);
}